// Round 10
// baseline (234.949 us; speedup 1.0000x reference)
//
#include <hip/hip_runtime.h>
#include <stdint.h>

#define NNODES 163842
#define INF 32
#define OUTF 32
#define KTOT 224
#define OPW 8            // outputs per thread (OUTF / 4 waves)

// Repack W [32, 224] row-major -> Wt2 phase-major:
// Wt2[((c*7 + j)*4 + t)*32 + o] = W[o*224 + j*32 + c*4 + t]
__global__ void repack_W_kernel(const float* __restrict__ W,
                                float* __restrict__ Wt2) {
    int i = blockIdx.x * blockDim.x + threadIdx.x;
    if (i < KTOT * OUTF) {
        int kk = i >> 5;          // 0..223
        int oo = i & 31;
        int j = kk >> 5;          // neighbor 0..6
        int f = kk & 31;          // feature 0..31
        int c = f >> 2;           // chunk 0..7
        int t = f & 3;
        Wt2[(((c * 7 + j) << 2) + t) * 32 + oo] = W[oo * KTOT + kk];
    }
}

// One asm global load, 16B, address + literal byte offset.
#define LOADX4(dst, addr, OFFSTR)                                            \
    asm volatile("global_load_dwordx4 %0, %1, off offset:" OFFSTR           \
                 : "=v"(dst) : "v"(addr))

// Issue chunk OFFSTR (byte offset = c*16) of all 7 rows into buf[0..6].
#define ISSUE(buf, OFFSTR)                                                   \
    LOADX4(buf[0], a0, OFFSTR); LOADX4(buf[1], a1, OFFSTR);                  \
    LOADX4(buf[2], a2, OFFSTR); LOADX4(buf[3], a3, OFFSTR);                  \
    LOADX4(buf[4], a4, OFFSTR); LOADX4(buf[5], a5, OFFSTR);                  \
    LOADX4(buf[6], a6, OFFSTR)

#define WAITVM(NSTR)                                                         \
    asm volatile("s_waitcnt vmcnt(" NSTR ")");                               \
    __builtin_amdgcn_sched_barrier(0)

// 224 FMAs for phase c from buf (static indexing only).
#define COMPUTE(buf, c)                                                      \
    _Pragma("unroll")                                                        \
    for (int j = 0; j < 7; ++j) {                                            \
        const float* vf = (const float*)&buf[j];                             \
        _Pragma("unroll")                                                    \
        for (int t = 0; t < 4; ++t) {                                        \
            const float* wrow = Wt2 + ((((c) * 7 + j) << 2) + t) * 32 + og * OPW; \
            _Pragma("unroll")                                                \
            for (int o = 0; o < OPW; ++o)                                    \
                acc[o] = fmaf(vf[t], wrow[o], acc[o]);                       \
        }                                                                    \
    }

__global__ __launch_bounds__(256) void onering_asm_pipe_kernel(
    const float* __restrict__ x,
    const int* __restrict__ idx,
    const float* __restrict__ Wt2,
    const float* __restrict__ b,
    float* __restrict__ out) {
    const int lane = threadIdx.x & 63;
    const int og = __builtin_amdgcn_readfirstlane(threadIdx.x >> 6);  // 0..3
    const int n = blockIdx.x * 64 + lane;
    const bool valid = (n < NNODES);
    const int nc = valid ? n : (NNODES - 1);
    const int base = nc * 7;

    // 7 neighbor-row base addresses (compiler's idx loads complete before the
    // empty asm below, so my manual vmcnt counts are exact afterwards).
    const float* a0 = x + (size_t)idx[base + 0] * INF;
    const float* a1 = x + (size_t)idx[base + 1] * INF;
    const float* a2 = x + (size_t)idx[base + 2] * INF;
    const float* a3 = x + (size_t)idx[base + 3] * INF;
    const float* a4 = x + (size_t)idx[base + 4] * INF;
    const float* a5 = x + (size_t)idx[base + 5] * INF;
    const float* a6 = x + (size_t)idx[base + 6] * INF;
    asm volatile("" :: "v"(a0), "v"(a1), "v"(a2), "v"(a3),
                       "v"(a4), "v"(a5), "v"(a6));

    float acc[OPW];
#pragma unroll
    for (int o = 0; o < OPW; ++o) acc[o] = b[og * OPW + o];

    float4 bufA[7], bufB[7];

    // prologue: phases 0 and 1 in flight (14 outstanding)
    ISSUE(bufA, "0");
    ISSUE(bufB, "16");

    WAITVM("7");  COMPUTE(bufA, 0);  ISSUE(bufA, "32");
    WAITVM("7");  COMPUTE(bufB, 1);  ISSUE(bufB, "48");
    WAITVM("7");  COMPUTE(bufA, 2);  ISSUE(bufA, "64");
    WAITVM("7");  COMPUTE(bufB, 3);  ISSUE(bufB, "80");
    WAITVM("7");  COMPUTE(bufA, 4);  ISSUE(bufA, "96");
    WAITVM("7");  COMPUTE(bufB, 5);  ISSUE(bufB, "112");
    WAITVM("7");  COMPUTE(bufA, 6);
    WAITVM("0");  COMPUTE(bufB, 7);

    if (valid) {
        float4* op = (float4*)(out + (size_t)n * OUTF + og * OPW);
        op[0] = *((float4*)&acc[0]);
        op[1] = *((float4*)&acc[4]);
    }
}

extern "C" void kernel_launch(void* const* d_in, const int* in_sizes, int n_in,
                              void* d_out, int out_size, void* d_ws, size_t ws_size,
                              hipStream_t stream) {
    const float* x   = (const float*)d_in[0];
    const int*   idx = (const int*)d_in[1];
    const float* W   = (const float*)d_in[2];
    const float* b   = (const float*)d_in[3];
    float* out = (float*)d_out;
    float* Wt2 = (float*)d_ws;   // 224*32 floats = 28 KB

    repack_W_kernel<<<(KTOT * OUTF + 255) / 256, 256, 0, stream>>>(W, Wt2);

    int grid = (NNODES + 63) / 64;  // 2561 blocks x 4 waves
    onering_asm_pipe_kernel<<<grid, 256, 0, stream>>>(x, idx, Wt2, b, out);
}

// Round 13
// 201.648 us; speedup vs baseline: 1.1651x; 1.1651x over previous
//
#include <hip/hip_runtime.h>

#define NNODES 163842
#define INF 32
#define OUTF 32
#define KTOT 224
#define OPW 8            // outputs per thread (OUTF / 4 waves)
#define NPB 64           // nodes per block
#define ROWS 448         // NPB*7 gathered rows
#define CHUNKS 3584      // ROWS*8 16B chunks
#define KPT 14           // CHUNKS / 256 threads

// Transpose W [32,224] -> Wt [224,32] (k-major) for wave-uniform scalar reads.
__global__ void transpose_W_kernel(const float* __restrict__ W,
                                   float* __restrict__ Wt) {
    int i = blockIdx.x * blockDim.x + threadIdx.x;
    if (i < KTOT * OUTF) {
        int k = i / OUTF;
        int o = i % OUTF;
        Wt[k * OUTF + o] = W[o * KTOT + k];
    }
}

// Block = 256 threads = 4 waves, 64 nodes.
// Phase A: stage the block's 448 neighbor indices into LDS (coalesced).
// Phase B: lane-parallel gather — each thread fetches 14 independent 16B
//          chunks (chunk g=t+k*256: row r=g>>3, slot c=g&7) and ds_writes
//          them at physical slot (c ^ (r&7)) — XOR swizzle for even banks.
// Phase C: per-node FMA from LDS; wave og computes outputs [og*8, og*8+8).
__global__ __launch_bounds__(256, 2) void onering_smem_kernel(
    const float* __restrict__ x,
    const int* __restrict__ idx,
    const float* __restrict__ Wt,
    const float* __restrict__ b,
    float* __restrict__ out) {
    __shared__ float ldsx[ROWS * INF];   // 57344 B
    __shared__ int   lidx[ROWS];         // 1792 B

    const int t = threadIdx.x;
    const int block0 = blockIdx.x * NPB;
    const int base7 = block0 * 7;

    // ---- Phase A: stage idx (clamped for the tail block) ----
    lidx[t] = idx[min(base7 + t, 7 * NNODES - 1)];
    if (t < ROWS - 256) {
        lidx[t + 256] = idx[min(base7 + t + 256, 7 * NNODES - 1)];
    }
    __syncthreads();

    // ---- Phase B: lane-parallel gather, 14 independent loads/thread ----
    float4 v[KPT];
#pragma unroll
    for (int k = 0; k < KPT; ++k) {
        const int g = t + (k << 8);
        const int r = g >> 3;
        const int c = g & 7;
        const int xi = lidx[r];                       // LDS read (lgkm dep only)
        v[k] = *(const float4*)(x + (size_t)xi * INF + (c << 2));
    }
#pragma unroll
    for (int k = 0; k < KPT; ++k) {
        const int g = t + (k << 8);
        const int r = g >> 3;
        const int c = g & 7;
        *(float4*)(ldsx + (r << 5) + (((c ^ (r & 7))) << 2)) = v[k];
    }
    // T19: cluster idx ds_reads, then all 14 global loads, then ds_writes —
    // keeps 14 loads in flight per thread instead of load/use serialization.
    __builtin_amdgcn_sched_group_barrier(0x100, KPT, 0);  // DS_READ
    __builtin_amdgcn_sched_group_barrier(0x020, KPT, 0);  // VMEM_READ
    __builtin_amdgcn_sched_group_barrier(0x200, KPT, 0);  // DS_WRITE
    __syncthreads();

    // ---- Phase C: compute ----
    const int lane = t & 63;
    const int og = __builtin_amdgcn_readfirstlane(t >> 6);  // 0..3
    const int n = lane;
    const int g = block0 + n;

    float acc[OPW];
#pragma unroll
    for (int o = 0; o < OPW; ++o) acc[o] = b[og * OPW + o];

#pragma unroll
    for (int j = 0; j < 7; ++j) {
        const int rn = n * 7 + j;
        const float* rowb = ldsx + (rn << 5);
        const int swz = rn & 7;
#pragma unroll
        for (int c = 0; c < 8; ++c) {
            float4 vv = *(const float4*)(rowb + ((c ^ swz) << 2));
            const float* vf = (const float*)&vv;
#pragma unroll
            for (int t4 = 0; t4 < 4; ++t4) {
                const float* wrow = Wt + (((j << 5) + (c << 2) + t4) << 5) + og * OPW;
#pragma unroll
                for (int o = 0; o < OPW; ++o)
                    acc[o] = fmaf(vf[t4], wrow[o], acc[o]);
            }
        }
    }

    if (g < NNODES) {
        float4* op = (float4*)(out + (size_t)g * OUTF + og * OPW);
        op[0] = *((float4*)&acc[0]);
        op[1] = *((float4*)&acc[4]);
    }
}

extern "C" void kernel_launch(void* const* d_in, const int* in_sizes, int n_in,
                              void* d_out, int out_size, void* d_ws, size_t ws_size,
                              hipStream_t stream) {
    const float* x   = (const float*)d_in[0];
    const int*   idx = (const int*)d_in[1];
    const float* W   = (const float*)d_in[2];
    const float* b   = (const float*)d_in[3];
    float* out = (float*)d_out;
    float* Wt  = (float*)d_ws;   // 224*32 floats = 28 KB

    transpose_W_kernel<<<(KTOT * OUTF + 255) / 256, 256, 0, stream>>>(W, Wt);

    int grid = (NNODES + NPB - 1) / NPB;  // 2561
    onering_smem_kernel<<<grid, 256, 0, stream>>>(x, idx, Wt, b, out);
}